// Round 8
// baseline (263.361 us; speedup 1.0000x reference)
//
#include <hip/hip_runtime.h>

// Neural stack, closed form. Round 13 (resubmit; prior attempt hit an infra
// container failure, no kernel verdict): MFMA reformulation.
// R7/R10/R11/R12 all pinned at 42-52us regardless of schedule/ILP/locality:
// the invariant was the wave-serial ballot->readlane->scatter-gather pipeline.
// R13 eliminates it: iterate j DESCENDING with lanes = t, so the pop-max and
// the coeff cutoff are per-lane running scalars (no scans, no ballots), emit
// the coeff matrix chunk [256t x 64j] to LDS as bf16, and do the read
// r[t][e] = sum_j coeff[t][j] * v[j][e] as a dense chunked GEMM on the
// matrix cores (mfma_f32_16x16x32_bf16), with chunk skipping once all rows
// of the tile have hit the sum(s)>=1 cutoff.
//
//   s_j^(t) = relu(d_j - relu(M - H_j)),  M = max_{j<tau<=t} G_tau (running),
//   coeff   = min(s, relu(1 - Cc)),       Cc = running sum of s (from top),
//   G_t = U_t - Dp_{t-1}, H_t = U_t - Dp_t  (f64 prefix sums of u, d).
//
// Block = (b, t-tile 256, e-half 128): 4 waves, each wave owns 64 t's
// (lane = t) for the recurrence and a 64t x 128e MFMA sub-tile. Grid 512,
// 2 blocks/CU. bf16 coeff/V vs threshold 0.1: ~0.01-0.03 abs error expected.

#define TT 512
#define BB 128
#define EE 256
#define LDC 72   // Cs row stride (bf16 elems), pad 8 to spread banks
#define LDV 72   // Vs row stride

typedef float v4f __attribute__((ext_vector_type(4)));
typedef float f4v __attribute__((ext_vector_type(4)));
typedef short s8v __attribute__((ext_vector_type(8)));

// packed per-(b,t): {G, H, d, 0}
__device__ v4f g_GHD[BB * TT];

__device__ __forceinline__ float readlanef(float v, int l) {
  return __int_as_float(__builtin_amdgcn_readlane(__float_as_int(v), l));
}

// f32 -> bf16, round to nearest even
__device__ __forceinline__ unsigned short f2bf(float x) {
  unsigned u = __float_as_uint(x);
  u += 0x7FFFu + ((u >> 16) & 1u);
  return (unsigned short)(u >> 16);
}

// ---------------------------------------------------------------------------
// Kernel A: per-batch f64 prefix sums of u,d -> packed (G,H,d) table.
// One wave per b.
// ---------------------------------------------------------------------------
__global__ __launch_bounds__(64) void precompute_kernel(
    const float* __restrict__ u, const float* __restrict__ d) {
  const int b = blockIdx.x;
  const int lane = threadIdx.x;

  double su[8], sv[8];
  float dv[8];
#pragma unroll
  for (int c = 0; c < 8; ++c) {
    const int t = c * 64 + lane;
    const float uv = u[t * BB + b];
    const float dd = d[t * BB + b];
    dv[c] = dd;
    su[c] = (double)uv;
    sv[c] = (double)dd;
  }
#pragma unroll
  for (int o = 1; o < 64; o <<= 1) {
#pragma unroll
    for (int c = 0; c < 8; ++c) {
      const double yu = __shfl_up(su[c], o);
      const double yv = __shfl_up(sv[c], o);
      if (lane >= o) { su[c] += yu; sv[c] += yv; }
    }
  }
  double oU = 0.0, oD = 0.0;
#pragma unroll
  for (int c = 0; c < 8; ++c) {
    const double U = oU + su[c];
    const double D = oD + sv[c];
    v4f w;
    w.x = (float)(U - (D - (double)dv[c]));  // G_t = U_t - Dp_{t-1}
    w.y = (float)(U - D);                    // H_t = U_t - Dp_t
    w.z = dv[c];
    w.w = 0.f;
    g_GHD[b * TT + c * 64 + lane] = w;
    oU += __shfl(su[c], 63);
    oD += __shfl(sv[c], 63);
  }
}

// ---------------------------------------------------------------------------
// Kernel B: recurrence + chunked MFMA GEMM.
// bid: b = bid>>2, z = bid&3 (z interleaved so light/heavy tiles alternate
// across CUs): tlo = (z>>1)*256, e0 = (z&1)*128.
// ---------------------------------------------------------------------------
__global__ __launch_bounds__(256, 2) void stack_mfma(
    const float* __restrict__ v, float* __restrict__ out) {
  const int bid = blockIdx.x;
  const int b = bid >> 2;
  const int z = bid & 3;
  const int tlo = (z >> 1) << 8;     // 0 or 256
  const int e0 = (z & 1) << 7;      // 0 or 128

  __shared__ __align__(16) unsigned short Cs[256 * LDC];  // coeff chunk
  __shared__ __align__(16) unsigned short Vs[128 * LDV];  // V chunk [e][k]
  __shared__ int flags[8];                                // ping-pong live

  const int tid = threadIdx.x;
  const int w = tid >> 6;
  const int lane = tid & 63;
  const int trow = (w << 6) | lane;   // C row (t within tile)
  const int t = tlo + trow;           // this lane's output row

  const v4f* __restrict__ GHD = g_GHD + b * TT;
  const float NI = -__builtin_inff();

  float Cc = 0.f;        // running sum of s (coeff cutoff at 1)
  float Mrun = NI;       // running max of G over (j, t]
  f4v acc[4][8];
#pragma unroll
  for (int mi = 0; mi < 4; ++mi)
#pragma unroll
    for (int ni = 0; ni < 8; ++ni)
      acc[mi][ni] = (f4v){0.f, 0.f, 0.f, 0.f};

  for (int jc = tlo + 192; jc >= 0; jc -= 64) {
    const int pp = ((jc >> 6) & 1) << 2;   // ping-pong flag bank
    const int mylive = __any((t >= jc) && (Cc < 1.f));
    if (lane == 0) flags[pp + w] = mylive;
    __syncthreads();
    const int blive = flags[pp] | flags[pp + 1] | flags[pp + 2] | flags[pp + 3];
    if (!blive) {
      if (jc <= tlo) break;   // everyone active and dead -> done
      continue;               // only pending lanes below -> skip chunk
    }

    // ---- stage V chunk [64 j x 128 e] -> Vs[e][k] bf16 (all threads) ----
    {
      const float* __restrict__ vp = v + ((size_t)jc * BB + b) * EE + e0;
#pragma unroll
      for (int it = 0; it < 8; ++it) {
        const int idx = tid + (it << 8);
        const int jr = idx >> 5;             // 0..63
        const int e4 = (idx & 31) << 2;      // 0..124
        const v4f x = *(const v4f*)(vp + (size_t)jr * (BB * EE) + e4);
        Vs[(e4 + 0) * LDV + jr] = f2bf(x.x);
        Vs[(e4 + 1) * LDV + jr] = f2bf(x.y);
        Vs[(e4 + 2) * LDV + jr] = f2bf(x.z);
        Vs[(e4 + 3) * LDV + jr] = f2bf(x.w);
      }
    }

    // ---- lane-local recurrence over j (descending), emit coeff to LDS ----
    if (mylive) {
      const v4f gh = GHD[jc + lane];   // 64 table entries; readlane-broadcast
#pragma unroll
      for (int g = 7; g >= 0; --g) {
        unsigned short hh[8];
#pragma unroll
        for (int q = 7; q >= 0; --q) {
          const int jj = (g << 3) | q;       // j = jc + jj, descending
          const float Gj = readlanef(gh.x, jj);
          const float Hj = readlanef(gh.y, jj);
          const float dj = readlanef(gh.z, jj);
          const bool act = (jc + jj) <= t;
          const float s = fmaxf(dj - fmaxf(Mrun - Hj, 0.f), 0.f);
          float cf = fminf(s, fmaxf(1.f - Cc, 0.f));
          if (act) {
            Cc += s;
            Mrun = fmaxf(Mrun, Gj);
          } else {
            cf = 0.f;
          }
          hh[q] = f2bf(cf);
        }
        uint4 pk;
        pk.x = (unsigned)hh[0] | ((unsigned)hh[1] << 16);
        pk.y = (unsigned)hh[2] | ((unsigned)hh[3] << 16);
        pk.z = (unsigned)hh[4] | ((unsigned)hh[5] << 16);
        pk.w = (unsigned)hh[6] | ((unsigned)hh[7] << 16);
        *(uint4*)&Cs[trow * LDC + (g << 3)] = pk;
      }
    }

    __syncthreads();

    // ---- MFMA: acc[64t x 128e] += C[64t x 64k] * V[64k x 128e] ----
    if (mylive) {
#pragma unroll
      for (int ks = 0; ks < 2; ++ks) {
        const int ko = (ks << 5) | ((lane >> 4) << 3);   // k offset per lane
        s8v a[4];
#pragma unroll
        for (int mi = 0; mi < 4; ++mi)
          a[mi] = *(const s8v*)&Cs[(((w << 6) | (mi << 4) | (lane & 15)) * LDC) + ko];
#pragma unroll
        for (int ni = 0; ni < 8; ++ni) {
          const s8v bfr = *(const s8v*)&Vs[(((ni << 4) | (lane & 15)) * LDV) + ko];
#pragma unroll
          for (int mi = 0; mi < 4; ++mi)
            acc[mi][ni] = __builtin_amdgcn_mfma_f32_16x16x32_bf16(
                a[mi], bfr, acc[mi][ni], 0, 0, 0);
        }
      }
    }
  }

  // ---- epilogue: D frag = {col = lane&15 (e), row = (lane>>4)*4 + r} ----
#pragma unroll
  for (int mi = 0; mi < 4; ++mi) {
    const int tt = tlo + (w << 6) + (mi << 4) + ((lane >> 4) << 2);
#pragma unroll
    for (int r = 0; r < 4; ++r) {
      float* op = out + ((size_t)(tt + r) * BB + b) * EE + e0 + (lane & 15);
#pragma unroll
      for (int ni = 0; ni < 8; ++ni)
        __builtin_nontemporal_store(acc[mi][ni][r], op + (ni << 4));
    }
  }
}

extern "C" void kernel_launch(void* const* d_in, const int* in_sizes, int n_in,
                              void* d_out, int out_size, void* d_ws,
                              size_t ws_size, hipStream_t stream) {
  const float* v = (const float*)d_in[0];
  const float* u = (const float*)d_in[1];
  const float* dd = (const float*)d_in[2];
  float* out = (float*)d_out;
  (void)in_sizes; (void)n_in; (void)out_size; (void)d_ws; (void)ws_size;

  hipLaunchKernelGGL(precompute_kernel, dim3(BB), dim3(64), 0, stream, u, dd);
  hipLaunchKernelGGL(stack_mfma, dim3(512), dim3(256), 0, stream, v, out);
}